// Round 14
// baseline (281.510 us; speedup 1.0000x reference)
//
#include <hip/hip_runtime.h>
#include <stdint.h>

// DynamicFc R20: R19 (16-sample blocks, 2 blocks/CU, correctness-verified) with
// the occupancy pinned TWO-SIDED: amdgpu_waves_per_eu(4,4).
//  R19 post-mortem: launch_bounds(512,4) is only a MINIMUM -> allocator chased
//  8 waves/EU, chose 64 VGPR, spilled af[4][4] (WRITE 279MB, mega 180us).
//  3x-confirmed compiler model: allocator maximizes imagined occupancy with no
//  spill-cost model; only waves_per_eu(min,max) bounds it from above.
//  min=4: VGPR<=128, 2 blocks/CU x 8 waves. max=4: forbids the 64-VGPR target.
//  R13's attribute suspicion was never convicted (identical-code control R9/R10
//  proved container flakes on valid binaries) -> clean retry, highest info.
//  Everything else identical to R19 (passed, absmax 0.094).
// B=8192, F=1024, LOW=128, MID=32. p1: j=l*32+m (j<4096), p2: j=4096+m*128+l.
// Fragment-major images: chunk(T,ks)[lane][8] = W[T*16+(lane&15)][ks*32+(lane>>4)*8..+8]
// Tripwires: VGPR == 128 (not 64!), WRITE ~33MB, FETCH ~77MB, Occ ~40%.

typedef __attribute__((ext_vector_type(8))) short bf16x8;
typedef __attribute__((ext_vector_type(4))) float f32x4;

#define MFMA(a, b, c) __builtin_amdgcn_mfma_f32_16x16x32_bf16((a), (b), (c), 0, 0, 0)

__device__ __forceinline__ ushort f2bf(float x) {
    union { float f; uint32_t u; } v; v.f = x;
    return (ushort)((v.u + 0x7FFFu + ((v.u >> 16) & 1u)) >> 16);
}
__device__ __forceinline__ ushort4 f2bf4(float4 v) {
    ushort4 o; o.x = f2bf(v.x); o.y = f2bf(v.y); o.z = f2bf(v.z); o.w = f2bf(v.w); return o;
}
__device__ __forceinline__ float bf2f(ushort u) {
    union { uint32_t i; float f; } v; v.i = ((uint32_t)u) << 16; return v.f;
}

// ---------------- K0: convert + fragment-major re-layout (verified) ----------------
__global__ __launch_bounds__(256) void k0_convert(
    const float* __restrict__ pgw, const float* __restrict__ wf,
    const float* __restrict__ wpf, const float* __restrict__ w2,
    ushort* __restrict__ pg_img, ushort* __restrict__ w_img, ushort* __restrict__ w2_img)
{
    int cid = blockIdx.x * 256 + threadIdx.x;   // 704*256 = 180224
    const float* src; ushort* dst;
    if (cid < 131072) {                                  // pg: 512*4*64
        int lane = cid & 63, ks = (cid >> 6) & 3, T = cid >> 8;
        int j = T * 16 + (lane & 15), k = ks * 32 + (lane >> 4) * 8;
        src = pgw + (size_t)j * 128 + k;
        dst = pg_img + (size_t)cid * 8;
    } else if (cid < 163840) {                           // wf/wpf: 2*8*32*64
        int c = cid - 131072;
        int lane = c & 63, ks = (c >> 6) & 31, lt = (c >> 11) & 7, mat = c >> 14;
        int l = lt * 16 + (lane & 15), k = ks * 32 + (lane >> 4) * 8;
        src = (mat ? wpf : wf) + (size_t)l * 1024 + k;
        dst = w_img + (size_t)c * 8;
    } else {                                             // w2: 64*4*64
        int c = cid - 163840;
        int lane = c & 63, ks = (c >> 6) & 3, nt = c >> 8;
        int n = nt * 16 + (lane & 15), k = ks * 32 + (lane >> 4) * 8;
        src = w2 + (size_t)n * 128 + k;
        dst = w2_img + (size_t)c * 8;
    }
    float4 a = ((const float4*)src)[0], b = ((const float4*)src)[1];
    ((ushort4*)dst)[0] = f2bf4(a);
    ((ushort4*)dst)[1] = f2bf4(b);
}

// ---------------- MEGA: one block = 16 samples end-to-end, 8 waves ----------------
// grid 512 x 512 threads; 2 blocks/CU, 4 waves/SIMD (pinned via waves_per_eu).
__global__ __launch_bounds__(512)
__attribute__((amdgpu_waves_per_eu(4, 4)))
void mega(
    const float* __restrict__ f, const float* __restrict__ pf,
    const ushort* __restrict__ w_img, const float* __restrict__ bfb,
    const float* __restrict__ bpfb, const ushort* __restrict__ pg_img,
    const float* __restrict__ pgb, const ushort* __restrict__ w2_img,
    const float* __restrict__ b2, float* __restrict__ out)
{
    __shared__ __align__(16) char smem[31744];
    // region0 (0..18432), phase-reused:
    //  A: As [16][520]us = 16640 | Tr [16][136]us = 4352 (after As dead)
    //  B: hred [4][32][17]f = 8704 @0 | hl [32][16]f = 2048 @8704
    //  C: gLDS [128][17]f = 8704 @0 (hred dead; hl @8704 disjoint)
    //  D: Ls [16][288]f = 18432 @0
    ushort* As    = (ushort*)smem;
    ushort* Tr    = (ushort*)smem;
    float*  hred  = (float*)smem;               // [4][32*17]
    float*  hl    = (float*)(smem + 8704);      // [32][16]
    float*  gLDS  = (float*)smem;               // [128][17]
    float*  Ls    = (float*)smem;               // [16][288]
    ushort* flowT = (ushort*)(smem + 18432);    // [128][20] bf16 = 5120 B
    ushort* pfrag = (ushort*)(smem + 23552);    // 4 chunks * 512 = 4096 B
    ushort* gfrag = (ushort*)(smem + 27648);    // 4 chunks * 512 = 4096 B

    const int tid = threadIdx.x;
    const int lane = tid & 63, wid = tid >> 6;   // wid 0..7
    const int q = lane >> 4, r15 = lane & 15;
    const int b0 = blockIdx.x * 16;

    // ================= Phase A: f_low / pf_low projections (stage-pipelined) ========
    {
        float4 vbuf[4];
#pragma unroll
        for (int rr = 0; rr < 4; rr++) {
            int row = rr * 4 + (tid >> 7);
            vbuf[rr] = *(const float4*)(f + (size_t)(b0 + row) * 1024 + (tid & 127) * 4);
        }
        f32x4 c;
        float bias_v = 0.f;
#pragma unroll
        for (int s = 0; s < 4; s++) {            // (mat,kh) = (0,0)(0,1)(1,0)(1,1)
            const int mat = s >> 1, kh = s & 1;
            if (kh == 0) {
                c = (f32x4){0.f, 0.f, 0.f, 0.f};
                bias_v = (mat ? bpfb : bfb)[wid * 16 + r15];
            }
            __syncthreads();                     // prior As readers done
#pragma unroll
            for (int rr = 0; rr < 4; rr++) {
                int row = rr * 4 + (tid >> 7);
                *(ushort4*)(As + row * 520 + (tid & 127) * 4) = f2bf4(vbuf[rr]);
            }
            __syncthreads();
            if (s < 3) {                         // issue NEXT stage loads (hide HBM)
                const int sn = s + 1, matn = sn >> 1, khn = sn & 1;
                const float* srcn = matn ? pf : f;
#pragma unroll
                for (int rr = 0; rr < 4; rr++) {
                    int row = rr * 4 + (tid >> 7);
                    vbuf[rr] = *(const float4*)(srcn + (size_t)(b0 + row) * 1024 + khn * 512 + (tid & 127) * 4);
                }
            }
            const ushort* wb = w_img + (size_t)mat * 131072 + ((size_t)wid * 32 + kh * 16) * 512;
            bf16x8 wfr[4];
#pragma unroll
            for (int p = 0; p < 4; p++) wfr[p] = *(const bf16x8*)(wb + (size_t)p * 512 + lane * 8);
#pragma unroll
            for (int ks = 0; ks < 16; ks++) {    // full unroll, ring-4
                const int cur = ks & 3;
                bf16x8 a0 = *(const bf16x8*)(As + (size_t)r15 * 520 + ks * 32 + q * 8);
                c = MFMA(a0, wfr[cur], c);
                if (ks + 4 < 16)
                    wfr[cur] = *(const bf16x8*)(wb + (size_t)(ks + 4) * 512 + lane * 8);
            }
            // C: row = b_local (q*4+r), col = l (wid*16 + r15)
            if (s == 1) {                        // mat0 epilogue -> flowT (disjoint)
                int l = wid * 16 + r15;
#pragma unroll
                for (int r = 0; r < 4; r++)
                    flowT[l * 20 + q * 4 + r] = f2bf(c[r] + bias_v);
            }
            if (s == 3) {                        // mat1 epilogue -> Tr -> pfrag
                __syncthreads();                 // all As reads done before Tr overwrite
                int l = wid * 16 + r15;
#pragma unroll
                for (int r = 0; r < 4; r++)
                    Tr[(q * 4 + r) * 136 + l] = f2bf(c[r] + bias_v);
                __syncthreads();
                if (wid < 4) {                   // emit pfrag: chunk ks2 = wid
                    int k0 = wid * 32 + (lane >> 4) * 8;
                    uint4 tv = *(const uint4*)(Tr + (size_t)(lane & 15) * 136 + k0);
                    *(uint4*)(pfrag + (size_t)wid * 512 + lane * 8) = tv;
                }
            }
        }
    }
    __syncthreads();   // pfrag/flowT visible to all waves

    // ========= Phase B: h — wave=(mh,lq), outer8 x inner4 ring-4, 4 partials ========
    bf16x8 bfr[4];     // pf_low fragments, held through B and C
#pragma unroll
    for (int ks = 0; ks < 4; ks++)
        bfr[ks] = *(const bf16x8*)(pfrag + (size_t)ks * 512 + lane * 8);

    {
        const int mh = wid & 1, lq = wid >> 1;   // m-half, l-quarter
        f32x4 hacc = (f32x4){0.f, 0.f, 0.f, 0.f};   // h[m=mh*16+q*4+r][b=r15]

        bf16x8 af[4][4];
        f32x4 bvr[4];
#pragma unroll
        for (int t = 0; t < 4; t++) {            // preload: p1 tile T = l*2 + mh
            const int T = (lq * 32 + t) * 2 + mh;
            const ushort* ap = pg_img + (size_t)T * 2048;
#pragma unroll
            for (int ks = 0; ks < 4; ks++)
                af[t][ks] = *(const bf16x8*)(ap + ks * 512 + lane * 8);
            bvr[t] = *(const f32x4*)(pgb + (size_t)T * 16 + q * 4);
        }
#pragma unroll 1
        for (int to = 0; to < 8; to++) {         // BOUNDED window
#pragma unroll
            for (int ti = 0; ti < 4; ti++) {     // ring idx (to*4+ti)&3 == ti: static
                const int t = to * 4 + ti;
                const int l = lq * 32 + t;
                f32x4 bv = bvr[ti];
                f32x4 cc = (f32x4){0.f, 0.f, 0.f, 0.f};
#pragma unroll
                for (int ks = 0; ks < 4; ks++) cc = MFMA(af[ti][ks], bfr[ks], cc);
                float s = bf2f(flowT[l * 20 + r15]);
#pragma unroll
                for (int r = 0; r < 4; r++) hacc[r] += s * (cc[r] + bv[r]);
                if (t + 4 < 32) {
                    const int Tn = (l + 4) * 2 + mh;
                    const ushort* ap = pg_img + (size_t)Tn * 2048;
#pragma unroll
                    for (int ks = 0; ks < 4; ks++)
                        af[ti][ks] = *(const bf16x8*)(ap + ks * 512 + lane * 8);
                    bvr[ti] = *(const f32x4*)(pgb + (size_t)Tn * 16 + q * 4);
                }
            }
        }
#pragma unroll
        for (int r = 0; r < 4; r++)
            hred[lq * 544 + (mh * 16 + q * 4 + r) * 17 + r15] = hacc[r];
    }
    __syncthreads();
    {   // 4-partial reduce + relu -> hl [32 m][16 b]; 512 threads, 1 float each
        int m = tid >> 4, bc = tid & 15;
        float s = 0.f;
#pragma unroll
        for (int w = 0; w < 4; w++) s += hred[w * 544 + m * 17 + bc];
        hl[m * 16 + bc] = fmaxf(s, 0.f);
    }
    __syncthreads();

    // ===== Phase C: g — wave owns l-tile wid, 32 m as outer8 x inner4 ring-4 ========
    {
        f32x4 gacc = (f32x4){0.f, 0.f, 0.f, 0.f};   // g[l=wid*16+q*4+r][b=r15]

        bf16x8 afc[4][4];
        f32x4 bvc[4];
#pragma unroll
        for (int t = 0; t < 4; t++) {            // preload: p2 tile T = 256 + m*8 + wid
            const ushort* ap = pg_img + (size_t)(256 + t * 8 + wid) * 2048;
#pragma unroll
            for (int ks = 0; ks < 4; ks++)
                afc[t][ks] = *(const bf16x8*)(ap + ks * 512 + lane * 8);
            bvc[t] = *(const f32x4*)(pgb + 4096 + (size_t)t * 128 + wid * 16 + q * 4);
        }
#pragma unroll 1
        for (int mo = 0; mo < 8; mo++) {         // BOUNDED window
#pragma unroll
            for (int mi = 0; mi < 4; mi++) {     // ring idx (mo*4+mi)&3 == mi: static
                const int m = mo * 4 + mi;
                f32x4 bv = bvc[mi];
                f32x4 cc = (f32x4){0.f, 0.f, 0.f, 0.f};
#pragma unroll
                for (int ks = 0; ks < 4; ks++) cc = MFMA(afc[mi][ks], bfr[ks], cc);
                float s = hl[m * 16 + r15];      // broadcast read
#pragma unroll
                for (int r = 0; r < 4; r++) gacc[r] += s * (cc[r] + bv[r]);
                if (m + 4 < 32) {
                    const int mn = m + 4;
                    const ushort* ap = pg_img + (size_t)(256 + mn * 8 + wid) * 2048;
#pragma unroll
                    for (int ks = 0; ks < 4; ks++)
                        afc[mi][ks] = *(const bf16x8*)(ap + ks * 512 + lane * 8);
                    bvc[mi] = *(const f32x4*)(pgb + 4096 + (size_t)mn * 128 + wid * 16 + q * 4);
                }
            }
        }
        // full m-sum done in-wave: write [16 l][16 b] patch to gLDS (pad 17)
#pragma unroll
        for (int r = 0; r < 4; r++)
            gLDS[(size_t)(wid * 16 + q * 4 + r) * 17 + r15] = gacc[r];
    }
    __syncthreads();
    if (wid < 4) {   // emit gfrag: chunk ksl = wid
        const int bloc = lane & 15;
        const int l0 = wid * 32 + (lane >> 4) * 8;
        ushort tmp[8];
#pragma unroll
        for (int e = 0; e < 8; e++)
            tmp[e] = f2bf(gLDS[(size_t)(l0 + e) * 17 + bloc]);
        ushort4 lo = {tmp[0], tmp[1], tmp[2], tmp[3]};
        ushort4 hi = {tmp[4], tmp[5], tmp[6], tmp[7]};
        ushort* dst = gfrag + (size_t)wid * 512 + lane * 8;
        ((ushort4*)dst)[0] = lo;
        ((ushort4*)dst)[1] = hi;
    }
    __syncthreads();

    // ================= Phase D: out (lean w2r, nb loop unroll 1) ====================
    {
        bf16x8 afg[4];
#pragma unroll
        for (int ks = 0; ks < 4; ks++)
            afg[ks] = *(const bf16x8*)(gfrag + (size_t)ks * 512 + lane * 8);

#pragma unroll 1
        for (int nb = 0; nb < 4; nb++) {         // BOUNDED window
            const int n0 = nb * 256;
            // early epilogue loads: land before the post-Ls barrier
            float4 fa[2], pa[2];
#pragma unroll
            for (int rr = 0; rr < 2; rr++) {
                const int b = b0 + wid * 2 + rr;
                const size_t gbase = (size_t)b * 1024 + n0 + lane * 4;
                fa[rr] = *(const float4*)(f + gbase);
                pa[rr] = *(const float4*)(pf + gbase);
            }
            float bias_v2[2];
#pragma unroll
            for (int nt = 0; nt < 2; nt++) bias_v2[nt] = b2[nb * 256 + wid * 32 + nt * 16 + r15];
            bf16x8 w2r[2][4];
#pragma unroll
            for (int nt = 0; nt < 2; nt++)
#pragma unroll
                for (int ks = 0; ks < 4; ks++)
                    w2r[nt][ks] = *(const bf16x8*)(w2_img + (size_t)((nb * 16 + wid * 2 + nt) * 4 + ks) * 512 + lane * 8);
#pragma unroll
            for (int nt = 0; nt < 2; nt++) {
                f32x4 cc = (f32x4){0.f, 0.f, 0.f, 0.f};
#pragma unroll
                for (int ks = 0; ks < 4; ks++) cc = MFMA(afg[ks], w2r[nt][ks], cc);
                const int nloc = wid * 32 + nt * 16 + r15;        // 0..255
                const int chunk = nloc >> 5, within = nloc & 31;
#pragma unroll
                for (int r = 0; r < 4; r++)
                    Ls[(size_t)(q * 4 + r) * 288 + chunk * 36 + within] = cc[r] + bias_v2[nt];
            }
            __syncthreads();
            {   // wave-contiguous epilogue: wave w rows w*2..+2, lane i <-> n0+4i
                const float* ls = Ls + (size_t)(wid * 2) * 288 + (lane >> 3) * 36 + (lane & 7) * 4;
#pragma unroll
                for (int rr = 0; rr < 2; rr++) {
                    const int b = b0 + wid * 2 + rr;
                    const size_t gbase = (size_t)b * 1024 + n0 + lane * 4;
                    float4 lv = *(const float4*)(ls + rr * 288);
                    float4 o;
                    o.x = lv.x + fa[rr].x + pa[rr].x; o.y = lv.y + fa[rr].y + pa[rr].y;
                    o.z = lv.z + fa[rr].z + pa[rr].z; o.w = lv.w + fa[rr].w + pa[rr].w;
                    *(float4*)(out + gbase) = o;
                }
            }
            __syncthreads();   // Ls reuse protection for next nb
        }
    }
}

// ---------------- launch ----------------
extern "C" void kernel_launch(void* const* d_in, const int* in_sizes, int n_in,
                              void* d_out, int out_size, void* d_ws, size_t ws_size,
                              hipStream_t stream)
{
    const float* f    = (const float*)d_in[0];
    const float* pf   = (const float*)d_in[1];
    const float* wf   = (const float*)d_in[2];
    const float* bfb  = (const float*)d_in[3];
    const float* wpf  = (const float*)d_in[4];
    const float* bpfb = (const float*)d_in[5];
    const float* w2   = (const float*)d_in[6];
    const float* b2   = (const float*)d_in[7];
    const float* pgw  = (const float*)d_in[8];
    const float* pgb  = (const float*)d_in[9];

    char* ws = (char*)d_ws;
    ushort* pg_img = (ushort*)(ws + 0);          // 2 MB
    ushort* w_img  = (ushort*)(ws + 2097152);    // 512 KB
    ushort* w2_img = (ushort*)(ws + 2621440);    // 256 KB
    float*  out    = (float*)d_out;

    k0_convert<<<dim3(704), dim3(256), 0, stream>>>(pgw, wf, wpf, w2, pg_img, w_img, w2_img);
    mega<<<dim3(512), dim3(512), 0, stream>>>(f, pf, w_img, bfb, bpfb,
                                              pg_img, pgb, w2_img, b2, out);
}

// Round 15
// 190.907 us; speedup vs baseline: 1.4746x; 1.4746x over previous
//
#include <hip/hip_runtime.h>
#include <stdint.h>

// DynamicFc R21: R19/R20 body (verified 2x) + LDS PADDED to 62464 to steer the
// register allocator.
//  R20 falsified waves_per_eu: VGPR stayed 64, spill unchanged. Assembling
//  R11/R12/R17/R18/R19/R20 pins the real heuristic: allocator targets the
//  LDS-DERIVED occupancy bound (min(floor(160KB/LDS), floor(2048/thr)) blocks
//  -> waves/EU) and sets VGPR to 512/waves_per_eu, ignoring launch_bounds mins
//  and waves_per_eu. R19 shrank LDS to 31744 -> bound 4 blocks -> 8 waves/EU
//  -> 64 VGPR -> spill. Fix: pad LDS to 62464 (only 31744 used): bound becomes
//  2 blocks -> 4 waves/EU -> 128-VGPR budget (R12/R17/R18 proved ~108-128
//  clean at this exact LDS size). HW still fits 2 blocks/CU (124928<=163840).
//  Everything else byte-identical to R20 minus the attribute.
// B=8192, F=1024, LOW=128, MID=32. p1: j=l*32+m (j<4096), p2: j=4096+m*128+l.
// Fragment-major images: chunk(T,ks)[lane][8] = W[T*16+(lane&15)][ks*32+(lane>>4)*8..+8]
// Tripwires: VGPR ~100-128 (NOT 64), WRITE ~33MB, FETCH ~77-90MB, Occ ~40%.

typedef __attribute__((ext_vector_type(8))) short bf16x8;
typedef __attribute__((ext_vector_type(4))) float f32x4;

#define MFMA(a, b, c) __builtin_amdgcn_mfma_f32_16x16x32_bf16((a), (b), (c), 0, 0, 0)

__device__ __forceinline__ ushort f2bf(float x) {
    union { float f; uint32_t u; } v; v.f = x;
    return (ushort)((v.u + 0x7FFFu + ((v.u >> 16) & 1u)) >> 16);
}
__device__ __forceinline__ ushort4 f2bf4(float4 v) {
    ushort4 o; o.x = f2bf(v.x); o.y = f2bf(v.y); o.z = f2bf(v.z); o.w = f2bf(v.w); return o;
}
__device__ __forceinline__ float bf2f(ushort u) {
    union { uint32_t i; float f; } v; v.i = ((uint32_t)u) << 16; return v.f;
}

// ---------------- K0: convert + fragment-major re-layout (verified) ----------------
__global__ __launch_bounds__(256) void k0_convert(
    const float* __restrict__ pgw, const float* __restrict__ wf,
    const float* __restrict__ wpf, const float* __restrict__ w2,
    ushort* __restrict__ pg_img, ushort* __restrict__ w_img, ushort* __restrict__ w2_img)
{
    int cid = blockIdx.x * 256 + threadIdx.x;   // 704*256 = 180224
    const float* src; ushort* dst;
    if (cid < 131072) {                                  // pg: 512*4*64
        int lane = cid & 63, ks = (cid >> 6) & 3, T = cid >> 8;
        int j = T * 16 + (lane & 15), k = ks * 32 + (lane >> 4) * 8;
        src = pgw + (size_t)j * 128 + k;
        dst = pg_img + (size_t)cid * 8;
    } else if (cid < 163840) {                           // wf/wpf: 2*8*32*64
        int c = cid - 131072;
        int lane = c & 63, ks = (c >> 6) & 31, lt = (c >> 11) & 7, mat = c >> 14;
        int l = lt * 16 + (lane & 15), k = ks * 32 + (lane >> 4) * 8;
        src = (mat ? wpf : wf) + (size_t)l * 1024 + k;
        dst = w_img + (size_t)c * 8;
    } else {                                             // w2: 64*4*64
        int c = cid - 163840;
        int lane = c & 63, ks = (c >> 6) & 3, nt = c >> 8;
        int n = nt * 16 + (lane & 15), k = ks * 32 + (lane >> 4) * 8;
        src = w2 + (size_t)n * 128 + k;
        dst = w2_img + (size_t)c * 8;
    }
    float4 a = ((const float4*)src)[0], b = ((const float4*)src)[1];
    ((ushort4*)dst)[0] = f2bf4(a);
    ((ushort4*)dst)[1] = f2bf4(b);
}

// ---------------- MEGA: one block = 16 samples end-to-end, 8 waves ----------------
// grid 512 x 512 threads; 2 blocks/CU, 4 waves/SIMD.
// LDS padded to 62464 so the allocator's LDS-occupancy bound = 2 blocks/CU
// -> 4 waves/EU -> 128-VGPR budget (no spill). Only first 31744 B are used.
__global__ __launch_bounds__(512, 2) void mega(
    const float* __restrict__ f, const float* __restrict__ pf,
    const ushort* __restrict__ w_img, const float* __restrict__ bfb,
    const float* __restrict__ bpfb, const ushort* __restrict__ pg_img,
    const float* __restrict__ pgb, const ushort* __restrict__ w2_img,
    const float* __restrict__ b2, float* __restrict__ out)
{
    __shared__ __align__(16) char smem[62464];   // PAD: used 31744, rest steers allocator
    // region0 (0..18432), phase-reused:
    //  A: As [16][520]us = 16640 | Tr [16][136]us = 4352 (after As dead)
    //  B: hred [4][32][17]f = 8704 @0 | hl [32][16]f = 2048 @8704
    //  C: gLDS [128][17]f = 8704 @0 (hred dead; hl @8704 disjoint)
    //  D: Ls [16][288]f = 18432 @0
    ushort* As    = (ushort*)smem;
    ushort* Tr    = (ushort*)smem;
    float*  hred  = (float*)smem;               // [4][32*17]
    float*  hl    = (float*)(smem + 8704);      // [32][16]
    float*  gLDS  = (float*)smem;               // [128][17]
    float*  Ls    = (float*)smem;               // [16][288]
    ushort* flowT = (ushort*)(smem + 18432);    // [128][20] bf16 = 5120 B
    ushort* pfrag = (ushort*)(smem + 23552);    // 4 chunks * 512 = 4096 B
    ushort* gfrag = (ushort*)(smem + 27648);    // 4 chunks * 512 = 4096 B

    const int tid = threadIdx.x;
    const int lane = tid & 63, wid = tid >> 6;   // wid 0..7
    const int q = lane >> 4, r15 = lane & 15;
    const int b0 = blockIdx.x * 16;

    // ================= Phase A: f_low / pf_low projections (stage-pipelined) ========
    {
        float4 vbuf[4];
#pragma unroll
        for (int rr = 0; rr < 4; rr++) {
            int row = rr * 4 + (tid >> 7);
            vbuf[rr] = *(const float4*)(f + (size_t)(b0 + row) * 1024 + (tid & 127) * 4);
        }
        f32x4 c;
        float bias_v = 0.f;
#pragma unroll
        for (int s = 0; s < 4; s++) {            // (mat,kh) = (0,0)(0,1)(1,0)(1,1)
            const int mat = s >> 1, kh = s & 1;
            if (kh == 0) {
                c = (f32x4){0.f, 0.f, 0.f, 0.f};
                bias_v = (mat ? bpfb : bfb)[wid * 16 + r15];
            }
            __syncthreads();                     // prior As readers done
#pragma unroll
            for (int rr = 0; rr < 4; rr++) {
                int row = rr * 4 + (tid >> 7);
                *(ushort4*)(As + row * 520 + (tid & 127) * 4) = f2bf4(vbuf[rr]);
            }
            __syncthreads();
            if (s < 3) {                         // issue NEXT stage loads (hide HBM)
                const int sn = s + 1, matn = sn >> 1, khn = sn & 1;
                const float* srcn = matn ? pf : f;
#pragma unroll
                for (int rr = 0; rr < 4; rr++) {
                    int row = rr * 4 + (tid >> 7);
                    vbuf[rr] = *(const float4*)(srcn + (size_t)(b0 + row) * 1024 + khn * 512 + (tid & 127) * 4);
                }
            }
            const ushort* wb = w_img + (size_t)mat * 131072 + ((size_t)wid * 32 + kh * 16) * 512;
            bf16x8 wfr[4];
#pragma unroll
            for (int p = 0; p < 4; p++) wfr[p] = *(const bf16x8*)(wb + (size_t)p * 512 + lane * 8);
#pragma unroll
            for (int ks = 0; ks < 16; ks++) {    // full unroll, ring-4
                const int cur = ks & 3;
                bf16x8 a0 = *(const bf16x8*)(As + (size_t)r15 * 520 + ks * 32 + q * 8);
                c = MFMA(a0, wfr[cur], c);
                if (ks + 4 < 16)
                    wfr[cur] = *(const bf16x8*)(wb + (size_t)(ks + 4) * 512 + lane * 8);
            }
            // C: row = b_local (q*4+r), col = l (wid*16 + r15)
            if (s == 1) {                        // mat0 epilogue -> flowT (disjoint)
                int l = wid * 16 + r15;
#pragma unroll
                for (int r = 0; r < 4; r++)
                    flowT[l * 20 + q * 4 + r] = f2bf(c[r] + bias_v);
            }
            if (s == 3) {                        // mat1 epilogue -> Tr -> pfrag
                __syncthreads();                 // all As reads done before Tr overwrite
                int l = wid * 16 + r15;
#pragma unroll
                for (int r = 0; r < 4; r++)
                    Tr[(q * 4 + r) * 136 + l] = f2bf(c[r] + bias_v);
                __syncthreads();
                if (wid < 4) {                   // emit pfrag: chunk ks2 = wid
                    int k0 = wid * 32 + (lane >> 4) * 8;
                    uint4 tv = *(const uint4*)(Tr + (size_t)(lane & 15) * 136 + k0);
                    *(uint4*)(pfrag + (size_t)wid * 512 + lane * 8) = tv;
                }
            }
        }
    }
    __syncthreads();   // pfrag/flowT visible to all waves

    // ========= Phase B: h — wave=(mh,lq), outer8 x inner4 ring-4, 4 partials ========
    bf16x8 bfr[4];     // pf_low fragments, held through B and C
#pragma unroll
    for (int ks = 0; ks < 4; ks++)
        bfr[ks] = *(const bf16x8*)(pfrag + (size_t)ks * 512 + lane * 8);

    {
        const int mh = wid & 1, lq = wid >> 1;   // m-half, l-quarter
        f32x4 hacc = (f32x4){0.f, 0.f, 0.f, 0.f};   // h[m=mh*16+q*4+r][b=r15]

        bf16x8 af[4][4];
        f32x4 bvr[4];
#pragma unroll
        for (int t = 0; t < 4; t++) {            // preload: p1 tile T = l*2 + mh
            const int T = (lq * 32 + t) * 2 + mh;
            const ushort* ap = pg_img + (size_t)T * 2048;
#pragma unroll
            for (int ks = 0; ks < 4; ks++)
                af[t][ks] = *(const bf16x8*)(ap + ks * 512 + lane * 8);
            bvr[t] = *(const f32x4*)(pgb + (size_t)T * 16 + q * 4);
        }
#pragma unroll 1
        for (int to = 0; to < 8; to++) {         // BOUNDED window
#pragma unroll
            for (int ti = 0; ti < 4; ti++) {     // ring idx (to*4+ti)&3 == ti: static
                const int t = to * 4 + ti;
                const int l = lq * 32 + t;
                f32x4 bv = bvr[ti];
                f32x4 cc = (f32x4){0.f, 0.f, 0.f, 0.f};
#pragma unroll
                for (int ks = 0; ks < 4; ks++) cc = MFMA(af[ti][ks], bfr[ks], cc);
                float s = bf2f(flowT[l * 20 + r15]);
#pragma unroll
                for (int r = 0; r < 4; r++) hacc[r] += s * (cc[r] + bv[r]);
                if (t + 4 < 32) {
                    const int Tn = (l + 4) * 2 + mh;
                    const ushort* ap = pg_img + (size_t)Tn * 2048;
#pragma unroll
                    for (int ks = 0; ks < 4; ks++)
                        af[ti][ks] = *(const bf16x8*)(ap + ks * 512 + lane * 8);
                    bvr[ti] = *(const f32x4*)(pgb + (size_t)Tn * 16 + q * 4);
                }
            }
        }
#pragma unroll
        for (int r = 0; r < 4; r++)
            hred[lq * 544 + (mh * 16 + q * 4 + r) * 17 + r15] = hacc[r];
    }
    __syncthreads();
    {   // 4-partial reduce + relu -> hl [32 m][16 b]; 512 threads, 1 float each
        int m = tid >> 4, bc = tid & 15;
        float s = 0.f;
#pragma unroll
        for (int w = 0; w < 4; w++) s += hred[w * 544 + m * 17 + bc];
        hl[m * 16 + bc] = fmaxf(s, 0.f);
    }
    __syncthreads();

    // ===== Phase C: g — wave owns l-tile wid, 32 m as outer8 x inner4 ring-4 ========
    {
        f32x4 gacc = (f32x4){0.f, 0.f, 0.f, 0.f};   // g[l=wid*16+q*4+r][b=r15]

        bf16x8 afc[4][4];
        f32x4 bvc[4];
#pragma unroll
        for (int t = 0; t < 4; t++) {            // preload: p2 tile T = 256 + m*8 + wid
            const ushort* ap = pg_img + (size_t)(256 + t * 8 + wid) * 2048;
#pragma unroll
            for (int ks = 0; ks < 4; ks++)
                afc[t][ks] = *(const bf16x8*)(ap + ks * 512 + lane * 8);
            bvc[t] = *(const f32x4*)(pgb + 4096 + (size_t)t * 128 + wid * 16 + q * 4);
        }
#pragma unroll 1
        for (int mo = 0; mo < 8; mo++) {         // BOUNDED window
#pragma unroll
            for (int mi = 0; mi < 4; mi++) {     // ring idx (mo*4+mi)&3 == mi: static
                const int m = mo * 4 + mi;
                f32x4 bv = bvc[mi];
                f32x4 cc = (f32x4){0.f, 0.f, 0.f, 0.f};
#pragma unroll
                for (int ks = 0; ks < 4; ks++) cc = MFMA(afc[mi][ks], bfr[ks], cc);
                float s = hl[m * 16 + r15];      // broadcast read
#pragma unroll
                for (int r = 0; r < 4; r++) gacc[r] += s * (cc[r] + bv[r]);
                if (m + 4 < 32) {
                    const int mn = m + 4;
                    const ushort* ap = pg_img + (size_t)(256 + mn * 8 + wid) * 2048;
#pragma unroll
                    for (int ks = 0; ks < 4; ks++)
                        afc[mi][ks] = *(const bf16x8*)(ap + ks * 512 + lane * 8);
                    bvc[mi] = *(const f32x4*)(pgb + 4096 + (size_t)mn * 128 + wid * 16 + q * 4);
                }
            }
        }
        // full m-sum done in-wave: write [16 l][16 b] patch to gLDS (pad 17)
#pragma unroll
        for (int r = 0; r < 4; r++)
            gLDS[(size_t)(wid * 16 + q * 4 + r) * 17 + r15] = gacc[r];
    }
    __syncthreads();
    if (wid < 4) {   // emit gfrag: chunk ksl = wid
        const int bloc = lane & 15;
        const int l0 = wid * 32 + (lane >> 4) * 8;
        ushort tmp[8];
#pragma unroll
        for (int e = 0; e < 8; e++)
            tmp[e] = f2bf(gLDS[(size_t)(l0 + e) * 17 + bloc]);
        ushort4 lo = {tmp[0], tmp[1], tmp[2], tmp[3]};
        ushort4 hi = {tmp[4], tmp[5], tmp[6], tmp[7]};
        ushort* dst = gfrag + (size_t)wid * 512 + lane * 8;
        ((ushort4*)dst)[0] = lo;
        ((ushort4*)dst)[1] = hi;
    }
    __syncthreads();

    // ================= Phase D: out (lean w2r, nb loop unroll 1) ====================
    {
        bf16x8 afg[4];
#pragma unroll
        for (int ks = 0; ks < 4; ks++)
            afg[ks] = *(const bf16x8*)(gfrag + (size_t)ks * 512 + lane * 8);

#pragma unroll 1
        for (int nb = 0; nb < 4; nb++) {         // BOUNDED window
            const int n0 = nb * 256;
            // early epilogue loads: land before the post-Ls barrier
            float4 fa[2], pa[2];
#pragma unroll
            for (int rr = 0; rr < 2; rr++) {
                const int b = b0 + wid * 2 + rr;
                const size_t gbase = (size_t)b * 1024 + n0 + lane * 4;
                fa[rr] = *(const float4*)(f + gbase);
                pa[rr] = *(const float4*)(pf + gbase);
            }
            float bias_v2[2];
#pragma unroll
            for (int nt = 0; nt < 2; nt++) bias_v2[nt] = b2[nb * 256 + wid * 32 + nt * 16 + r15];
            bf16x8 w2r[2][4];
#pragma unroll
            for (int nt = 0; nt < 2; nt++)
#pragma unroll
                for (int ks = 0; ks < 4; ks++)
                    w2r[nt][ks] = *(const bf16x8*)(w2_img + (size_t)((nb * 16 + wid * 2 + nt) * 4 + ks) * 512 + lane * 8);
#pragma unroll
            for (int nt = 0; nt < 2; nt++) {
                f32x4 cc = (f32x4){0.f, 0.f, 0.f, 0.f};
#pragma unroll
                for (int ks = 0; ks < 4; ks++) cc = MFMA(afg[ks], w2r[nt][ks], cc);
                const int nloc = wid * 32 + nt * 16 + r15;        // 0..255
                const int chunk = nloc >> 5, within = nloc & 31;
#pragma unroll
                for (int r = 0; r < 4; r++)
                    Ls[(size_t)(q * 4 + r) * 288 + chunk * 36 + within] = cc[r] + bias_v2[nt];
            }
            __syncthreads();
            {   // wave-contiguous epilogue: wave w rows w*2..+2, lane i <-> n0+4i
                const float* ls = Ls + (size_t)(wid * 2) * 288 + (lane >> 3) * 36 + (lane & 7) * 4;
#pragma unroll
                for (int rr = 0; rr < 2; rr++) {
                    const int b = b0 + wid * 2 + rr;
                    const size_t gbase = (size_t)b * 1024 + n0 + lane * 4;
                    float4 lv = *(const float4*)(ls + rr * 288);
                    float4 o;
                    o.x = lv.x + fa[rr].x + pa[rr].x; o.y = lv.y + fa[rr].y + pa[rr].y;
                    o.z = lv.z + fa[rr].z + pa[rr].z; o.w = lv.w + fa[rr].w + pa[rr].w;
                    *(float4*)(out + gbase) = o;
                }
            }
            __syncthreads();   // Ls reuse protection for next nb
        }
    }
}

// ---------------- launch ----------------
extern "C" void kernel_launch(void* const* d_in, const int* in_sizes, int n_in,
                              void* d_out, int out_size, void* d_ws, size_t ws_size,
                              hipStream_t stream)
{
    const float* f    = (const float*)d_in[0];
    const float* pf   = (const float*)d_in[1];
    const float* wf   = (const float*)d_in[2];
    const float* bfb  = (const float*)d_in[3];
    const float* wpf  = (const float*)d_in[4];
    const float* bpfb = (const float*)d_in[5];
    const float* w2   = (const float*)d_in[6];
    const float* b2   = (const float*)d_in[7];
    const float* pgw  = (const float*)d_in[8];
    const float* pgb  = (const float*)d_in[9];

    char* ws = (char*)d_ws;
    ushort* pg_img = (ushort*)(ws + 0);          // 2 MB
    ushort* w_img  = (ushort*)(ws + 2097152);    // 512 KB
    ushort* w2_img = (ushort*)(ws + 2621440);    // 256 KB
    float*  out    = (float*)d_out;

    k0_convert<<<dim3(704), dim3(256), 0, stream>>>(pgw, wf, wpf, w2, pg_img, w_img, w2_img);
    mega<<<dim3(512), dim3(512), 0, stream>>>(f, pf, w_img, bfb, bpfb,
                                              pg_img, pgb, w2_img, b2, out);
}

// Round 18
// 172.917 us; speedup vs baseline: 1.6280x; 1.1040x over previous
//
#include <hip/hip_runtime.h>
#include <stdint.h>

// DynamicFc R26: RETRY of R24 (R18 split at B|C for per-phase visibility).
//  R24's "container failed twice" had no identified defect on full re-audit:
//  LDS <= 62464 (R18-verified size), all indices bounded, ws 6.03MB << ~20MB,
//  no sync constructs, stream-ordering gives ab->cd. Failure signature matches
//  the PROVEN flake class (R9 failed; byte-identical R10 passed and produced
//  the key data; infra timings show bursts: 680s pushes, 150s acquires).
//  One clean retry. If it fails again, fall back to verified R18 as plateau.
//  Rationale for the split (unchanged): R18's mega=71us has ~40us unattributed;
//  5 theory-first rounds (barriers, TLPx3, allocator) all failed to move it =>
//  buy phase-resolved counters (methodology: ablate before optimizing).
//  mega_ab (A+B) writes hl->h_g (1MB) + pfrag->pf_g (2MB); mega_cd (C+D)
//  reads them. Bodies R18-VERBATIM; both 62464B LDS + launch_bounds(512,2)
//  preserving the proven 128-VGPR allocator target.
// B=8192, F=1024, LOW=128, MID=32. p1: j=l*32+m (j<4096), p2: j=4096+m*128+l.
// Fragment-major images: chunk(T,ks)[lane][8] = W[T*16+(lane&15)][ks*32+(lane>>4)*8..+8]
// Tripwires: VGPR<=128 both, ab WRITE ~3MB / cd WRITE ~33MB, no spill blowup.

typedef __attribute__((ext_vector_type(8))) short bf16x8;
typedef __attribute__((ext_vector_type(4))) float f32x4;

#define MFMA(a, b, c) __builtin_amdgcn_mfma_f32_16x16x32_bf16((a), (b), (c), 0, 0, 0)

__device__ __forceinline__ ushort f2bf(float x) {
    union { float f; uint32_t u; } v; v.f = x;
    return (ushort)((v.u + 0x7FFFu + ((v.u >> 16) & 1u)) >> 16);
}
__device__ __forceinline__ ushort4 f2bf4(float4 v) {
    ushort4 o; o.x = f2bf(v.x); o.y = f2bf(v.y); o.z = f2bf(v.z); o.w = f2bf(v.w); return o;
}
__device__ __forceinline__ float bf2f(ushort u) {
    union { uint32_t i; float f; } v; v.i = ((uint32_t)u) << 16; return v.f;
}

// ---------------- K0: convert + fragment-major re-layout (verified) ----------------
__global__ __launch_bounds__(256) void k0_convert(
    const float* __restrict__ pgw, const float* __restrict__ wf,
    const float* __restrict__ wpf, const float* __restrict__ w2,
    ushort* __restrict__ pg_img, ushort* __restrict__ w_img, ushort* __restrict__ w2_img)
{
    int cid = blockIdx.x * 256 + threadIdx.x;   // 704*256 = 180224
    const float* src; ushort* dst;
    if (cid < 131072) {                                  // pg: 512*4*64
        int lane = cid & 63, ks = (cid >> 6) & 3, T = cid >> 8;
        int j = T * 16 + (lane & 15), k = ks * 32 + (lane >> 4) * 8;
        src = pgw + (size_t)j * 128 + k;
        dst = pg_img + (size_t)cid * 8;
    } else if (cid < 163840) {                           // wf/wpf: 2*8*32*64
        int c = cid - 131072;
        int lane = c & 63, ks = (c >> 6) & 31, lt = (c >> 11) & 7, mat = c >> 14;
        int l = lt * 16 + (lane & 15), k = ks * 32 + (lane >> 4) * 8;
        src = (mat ? wpf : wf) + (size_t)l * 1024 + k;
        dst = w_img + (size_t)c * 8;
    } else {                                             // w2: 64*4*64
        int c = cid - 163840;
        int lane = c & 63, ks = (c >> 6) & 3, nt = c >> 8;
        int n = nt * 16 + (lane & 15), k = ks * 32 + (lane >> 4) * 8;
        src = w2 + (size_t)n * 128 + k;
        dst = w2_img + (size_t)c * 8;
    }
    float4 a = ((const float4*)src)[0], b = ((const float4*)src)[1];
    ((ushort4*)dst)[0] = f2bf4(a);
    ((ushort4*)dst)[1] = f2bf4(b);
}

// ---------------- MEGA_AB: Phase A (projections) + Phase B (h) ----------------
// grid 256 x 512 threads; 1 block/CU, 2 waves/SIMD. LDS 62464 (R18 layout).
__global__ __launch_bounds__(512, 2) void mega_ab(
    const float* __restrict__ f, const float* __restrict__ pf,
    const ushort* __restrict__ w_img, const float* __restrict__ bfb,
    const float* __restrict__ bpfb, const ushort* __restrict__ pg_img,
    const float* __restrict__ pgb,
    float* __restrict__ h_g /*[256][1024]*/, ushort* __restrict__ pf_g /*[256][4096]*/)
{
    __shared__ __align__(16) char smem[62464];
    // A: As [32][520]us = 33280 | Tr [32][136]us (after As dead)
    // B: hred [4][32][33]f = 16896 @0
    ushort* As    = (ushort*)smem;
    ushort* Tr    = (ushort*)smem;
    float*  hred  = (float*)smem;               // [4][32*33]
    ushort* flowT = (ushort*)(smem + 36864);    // [128][36] bf16 = 9216 B
    ushort* pfrag = (ushort*)(smem + 46080);    // 8 chunks * 512 = 8192 B

    const int tid = threadIdx.x;
    const int lane = tid & 63, wid = tid >> 6;   // wid 0..7
    const int q = lane >> 4, r15 = lane & 15;
    const int b0 = blockIdx.x * 32;

    // ================= Phase A (R18-verbatim, stage-pipelined) =================
    {
        float4 vbuf[8];
#pragma unroll
        for (int rr = 0; rr < 8; rr++) {
            int row = rr * 4 + (tid >> 7);
            vbuf[rr] = *(const float4*)(f + (size_t)(b0 + row) * 1024 + (tid & 127) * 4);
        }
        f32x4 c[2];
        float bias_v = 0.f;
#pragma unroll
        for (int s = 0; s < 4; s++) {            // (mat,kh) = (0,0)(0,1)(1,0)(1,1)
            const int mat = s >> 1, kh = s & 1;
            if (kh == 0) {
                c[0] = (f32x4){0.f, 0.f, 0.f, 0.f};
                c[1] = (f32x4){0.f, 0.f, 0.f, 0.f};
                bias_v = (mat ? bpfb : bfb)[wid * 16 + r15];
            }
            __syncthreads();                     // prior As readers done
#pragma unroll
            for (int rr = 0; rr < 8; rr++) {
                int row = rr * 4 + (tid >> 7);
                *(ushort4*)(As + row * 520 + (tid & 127) * 4) = f2bf4(vbuf[rr]);
            }
            __syncthreads();
            if (s < 3) {                         // issue NEXT stage loads (hide HBM)
                const int sn = s + 1, matn = sn >> 1, khn = sn & 1;
                const float* srcn = matn ? pf : f;
#pragma unroll
                for (int rr = 0; rr < 8; rr++) {
                    int row = rr * 4 + (tid >> 7);
                    vbuf[rr] = *(const float4*)(srcn + (size_t)(b0 + row) * 1024 + khn * 512 + (tid & 127) * 4);
                }
            }
            const ushort* wb = w_img + (size_t)mat * 131072 + ((size_t)wid * 32 + kh * 16) * 512;
            bf16x8 wfr[4];
#pragma unroll
            for (int p = 0; p < 4; p++) wfr[p] = *(const bf16x8*)(wb + (size_t)p * 512 + lane * 8);
#pragma unroll
            for (int ks = 0; ks < 16; ks++) {    // full unroll, ring-4
                const int cur = ks & 3;
                bf16x8 a0 = *(const bf16x8*)(As + (size_t)r15 * 520 + ks * 32 + q * 8);
                bf16x8 a1 = *(const bf16x8*)(As + (size_t)(16 + r15) * 520 + ks * 32 + q * 8);
                c[0] = MFMA(a0, wfr[cur], c[0]);
                c[1] = MFMA(a1, wfr[cur], c[1]);
                if (ks + 4 < 16)
                    wfr[cur] = *(const bf16x8*)(wb + (size_t)(ks + 4) * 512 + lane * 8);
            }
            // C: row = b_local (mt*16 + q*4 + r), col = l (wid*16 + r15)
            if (s == 1) {                        // mat0 epilogue -> flowT (disjoint)
                int l = wid * 16 + r15;
#pragma unroll
                for (int mt = 0; mt < 2; mt++)
#pragma unroll
                    for (int r = 0; r < 4; r++)
                        flowT[l * 36 + mt * 16 + q * 4 + r] = f2bf(c[mt][r] + bias_v);
            }
            if (s == 3) {                        // mat1 epilogue -> Tr -> pfrag (+global)
                __syncthreads();                 // all As reads done before Tr overwrite
                int l = wid * 16 + r15;
#pragma unroll
                for (int mt = 0; mt < 2; mt++)
#pragma unroll
                    for (int r = 0; r < 4; r++)
                        Tr[(mt * 16 + q * 4 + r) * 136 + l] = f2bf(c[mt][r] + bias_v);
                __syncthreads();
                // emit pfrag: one chunk per wave (chunkid = wid = bt*4 + ks2)
                int bt = wid >> 2, ks2 = wid & 3;
                int k0 = ks2 * 32 + (lane >> 4) * 8;
                uint4 tv = *(const uint4*)(Tr + (size_t)(bt * 16 + (lane & 15)) * 136 + k0);
                *(uint4*)(pfrag + (size_t)wid * 512 + lane * 8) = tv;
                *(uint4*)(pf_g + (size_t)blockIdx.x * 4096 + (size_t)wid * 512 + lane * 8) = tv;
            }
        }
    }
    __syncthreads();   // pfrag/flowT visible to all waves

    // ========= Phase B (R18-verbatim): wave=(mh,lq), ring-4, 4 partials ========
    bf16x8 bfr[2][4];
#pragma unroll
    for (int ct = 0; ct < 2; ct++)
#pragma unroll
        for (int ks = 0; ks < 4; ks++)
            bfr[ct][ks] = *(const bf16x8*)(pfrag + (size_t)(ct * 4 + ks) * 512 + lane * 8);

    {
        const int mh = wid & 1, lq = wid >> 1;   // m-half, l-quarter
        f32x4 hacc[2];                           // [ct]
        hacc[0] = (f32x4){0.f, 0.f, 0.f, 0.f};
        hacc[1] = (f32x4){0.f, 0.f, 0.f, 0.f};

        bf16x8 af[4][4];
        f32x4 bvr[4];
#pragma unroll
        for (int t = 0; t < 4; t++) {            // preload: p1 tile T = l*2 + mh
            const int T = (lq * 32 + t) * 2 + mh;
            const ushort* ap = pg_img + (size_t)T * 2048;
#pragma unroll
            for (int ks = 0; ks < 4; ks++)
                af[t][ks] = *(const bf16x8*)(ap + ks * 512 + lane * 8);
            bvr[t] = *(const f32x4*)(pgb + (size_t)T * 16 + q * 4);
        }
#pragma unroll 1
        for (int to = 0; to < 8; to++) {         // BOUNDED window
#pragma unroll
            for (int ti = 0; ti < 4; ti++) {     // ring idx (to*4+ti)&3 == ti: static
                const int t = to * 4 + ti;
                const int l = lq * 32 + t;
                f32x4 bv = bvr[ti];
#pragma unroll
                for (int ct = 0; ct < 2; ct++) {
                    f32x4 cc = (f32x4){0.f, 0.f, 0.f, 0.f};
#pragma unroll
                    for (int ks = 0; ks < 4; ks++) cc = MFMA(af[ti][ks], bfr[ct][ks], cc);
                    float s = bf2f(flowT[l * 36 + ct * 16 + r15]);
#pragma unroll
                    for (int r = 0; r < 4; r++) hacc[ct][r] += s * (cc[r] + bv[r]);
                }
                if (t + 4 < 32) {
                    const int Tn = (l + 4) * 2 + mh;
                    const ushort* ap = pg_img + (size_t)Tn * 2048;
#pragma unroll
                    for (int ks = 0; ks < 4; ks++)
                        af[ti][ks] = *(const bf16x8*)(ap + ks * 512 + lane * 8);
                    bvr[ti] = *(const f32x4*)(pgb + (size_t)Tn * 16 + q * 4);
                }
            }
        }
#pragma unroll
        for (int ct = 0; ct < 2; ct++)
#pragma unroll
            for (int r = 0; r < 4; r++)
                hred[lq * 1056 + (mh * 16 + q * 4 + r) * 33 + ct * 16 + r15] = hacc[ct][r];
    }
    __syncthreads();
    {   // 4-partial reduce + relu -> h_g (coalesced: 2 consecutive floats/thread)
        int m = tid >> 4, bc = (tid & 15) * 2;
        float s0 = 0.f, s1 = 0.f;
#pragma unroll
        for (int w = 0; w < 4; w++) {
            s0 += hred[w * 1056 + m * 33 + bc];
            s1 += hred[w * 1056 + m * 33 + bc + 1];
        }
        float2 hv;
        hv.x = fmaxf(s0, 0.f);
        hv.y = fmaxf(s1, 0.f);
        *(float2*)(h_g + (size_t)blockIdx.x * 1024 + m * 32 + bc) = hv;
    }
}

// ---------------- MEGA_CD: Phase C (g) + Phase D (out) ----------------
// grid 256 x 512 threads; LDS padded to 62464 (same allocator target).
__global__ __launch_bounds__(512, 2) void mega_cd(
    const float* __restrict__ f, const float* __restrict__ pf,
    const ushort* __restrict__ pg_img, const float* __restrict__ pgb,
    const ushort* __restrict__ w2_img, const float* __restrict__ b2,
    const float* __restrict__ h_g, const ushort* __restrict__ pf_g,
    float* __restrict__ out)
{
    __shared__ __align__(16) char smem[62464];   // pad: same allocator target as R18
    // hl [32][32]f = 4096 @0 | gLDS [128][33]f = 16896 @4096 | Ls [32][288]f @0
    float*  hl    = (float*)smem;
    float*  gLDS  = (float*)(smem + 4096);
    float*  Ls    = (float*)smem;
    ushort* gfrag = (ushort*)(smem + 54272);    // 8 chunks * 512 = 8192 B

    const int tid = threadIdx.x;
    const int lane = tid & 63, wid = tid >> 6;   // wid 0..7
    const int q = lane >> 4, r15 = lane & 15;
    const int b0 = blockIdx.x * 32;

    // load hl from h_g (coalesced float2/thread)
    {
        float2 hv = *(const float2*)(h_g + (size_t)blockIdx.x * 1024 + tid * 2);
        *(float2*)(hl + tid * 2) = hv;
    }
    // pf_low fragments from pf_g (global, L2-resident)
    bf16x8 bfr[2][4];
#pragma unroll
    for (int ct = 0; ct < 2; ct++)
#pragma unroll
        for (int ks = 0; ks < 4; ks++)
            bfr[ct][ks] = *(const bf16x8*)(pf_g + (size_t)blockIdx.x * 4096 + (size_t)(ct * 4 + ks) * 512 + lane * 8);
    __syncthreads();

    // ===== Phase C (R18-verbatim): wave owns l-tile wid, 32 m, ring-4 ========
    {
        f32x4 gacc[2];                           // [ct]
        gacc[0] = (f32x4){0.f, 0.f, 0.f, 0.f};
        gacc[1] = (f32x4){0.f, 0.f, 0.f, 0.f};

        bf16x8 afc[4][4];
        f32x4 bvc[4];
#pragma unroll
        for (int t = 0; t < 4; t++) {            // preload: p2 tile T = 256 + m*8 + wid
            const ushort* ap = pg_img + (size_t)(256 + t * 8 + wid) * 2048;
#pragma unroll
            for (int ks = 0; ks < 4; ks++)
                afc[t][ks] = *(const bf16x8*)(ap + ks * 512 + lane * 8);
            bvc[t] = *(const f32x4*)(pgb + 4096 + (size_t)t * 128 + wid * 16 + q * 4);
        }
#pragma unroll 1
        for (int mo = 0; mo < 8; mo++) {         // BOUNDED window
#pragma unroll
            for (int mi = 0; mi < 4; mi++) {     // ring idx (mo*4+mi)&3 == mi: static
                const int m = mo * 4 + mi;
                f32x4 bv = bvc[mi];
#pragma unroll
                for (int ct = 0; ct < 2; ct++) {
                    f32x4 cc = (f32x4){0.f, 0.f, 0.f, 0.f};
#pragma unroll
                    for (int ks = 0; ks < 4; ks++) cc = MFMA(afc[mi][ks], bfr[ct][ks], cc);
                    float s = hl[m * 32 + ct * 16 + r15];   // broadcast read
#pragma unroll
                    for (int r = 0; r < 4; r++) gacc[ct][r] += s * (cc[r] + bv[r]);
                }
                if (m + 4 < 32) {
                    const int mn = m + 4;
                    const ushort* ap = pg_img + (size_t)(256 + mn * 8 + wid) * 2048;
#pragma unroll
                    for (int ks = 0; ks < 4; ks++)
                        afc[mi][ks] = *(const bf16x8*)(ap + ks * 512 + lane * 8);
                    bvc[mi] = *(const f32x4*)(pgb + 4096 + (size_t)mn * 128 + wid * 16 + q * 4);
                }
            }
        }
        // full m-sum done in-wave: write [16 l][32 b] patch to gLDS (pad 33)
#pragma unroll
        for (int ct = 0; ct < 2; ct++)
#pragma unroll
            for (int r = 0; r < 4; r++)
                gLDS[(size_t)(wid * 16 + q * 4 + r) * 33 + ct * 16 + r15] = gacc[ct][r];
    }
    __syncthreads();
    {   // emit gfrag: chunk wid = (bt = wid>>2, ksl = wid&3)
        const int bt = wid >> 2, ksl = wid & 3;
        const int bloc = bt * 16 + (lane & 15);
        const int l0 = ksl * 32 + (lane >> 4) * 8;
        ushort tmp[8];
#pragma unroll
        for (int e = 0; e < 8; e++)
            tmp[e] = f2bf(gLDS[(size_t)(l0 + e) * 33 + bloc]);
        ushort4 lo = {tmp[0], tmp[1], tmp[2], tmp[3]};
        ushort4 hi = {tmp[4], tmp[5], tmp[6], tmp[7]};
        ushort* dst = gfrag + (size_t)wid * 512 + lane * 8;
        ((ushort4*)dst)[0] = lo;
        ((ushort4*)dst)[1] = hi;
    }
    __syncthreads();

    // ================= Phase D (R18-verbatim): out = g@W2^T + b2 + f + pf ===========
    {
        bf16x8 afg[2][4];
#pragma unroll
        for (int mtl = 0; mtl < 2; mtl++)
#pragma unroll
            for (int ks = 0; ks < 4; ks++)
                afg[mtl][ks] = *(const bf16x8*)(gfrag + (size_t)(mtl * 4 + ks) * 512 + lane * 8);

#pragma unroll 1
        for (int nb = 0; nb < 4; nb++) {         // BOUNDED window
            const int n0 = nb * 256;
            // early epilogue loads: land before the post-Ls barrier
            float4 fa[4], pa[4];
#pragma unroll
            for (int rr = 0; rr < 4; rr++) {
                const int b = b0 + wid * 4 + rr;
                const size_t gbase = (size_t)b * 1024 + n0 + lane * 4;
                fa[rr] = *(const float4*)(f + gbase);
                pa[rr] = *(const float4*)(pf + gbase);
            }
            float bias_v2[2];
#pragma unroll
            for (int nt = 0; nt < 2; nt++) bias_v2[nt] = b2[nb * 256 + wid * 32 + nt * 16 + r15];
            bf16x8 w2r[2][4];
#pragma unroll
            for (int nt = 0; nt < 2; nt++)
#pragma unroll
                for (int ks = 0; ks < 4; ks++)
                    w2r[nt][ks] = *(const bf16x8*)(w2_img + (size_t)((nb * 16 + wid * 2 + nt) * 4 + ks) * 512 + lane * 8);
#pragma unroll
            for (int nt = 0; nt < 2; nt++) {
#pragma unroll
                for (int mtl = 0; mtl < 2; mtl++) {
                    f32x4 cc = (f32x4){0.f, 0.f, 0.f, 0.f};
#pragma unroll
                    for (int ks = 0; ks < 4; ks++) cc = MFMA(afg[mtl][ks], w2r[nt][ks], cc);
                    const int nloc = wid * 32 + nt * 16 + r15;        // 0..255
                    const int chunk = nloc >> 5, within = nloc & 31;
#pragma unroll
                    for (int r = 0; r < 4; r++)
                        Ls[(size_t)(mtl * 16 + q * 4 + r) * 288 + chunk * 36 + within] = cc[r] + bias_v2[nt];
                }
            }
            __syncthreads();
            {   // wave-contiguous epilogue: wave w rows w*4..+4, lane i <-> n0+4i
                const float* ls = Ls + (size_t)(wid * 4) * 288 + (lane >> 3) * 36 + (lane & 7) * 4;
#pragma unroll
                for (int rr = 0; rr < 4; rr++) {
                    const int b = b0 + wid * 4 + rr;
                    const size_t gbase = (size_t)b * 1024 + n0 + lane * 4;
                    float4 lv = *(const float4*)(ls + rr * 288);
                    float4 o;
                    o.x = lv.x + fa[rr].x + pa[rr].x; o.y = lv.y + fa[rr].y + pa[rr].y;
                    o.z = lv.z + fa[rr].z + pa[rr].z; o.w = lv.w + fa[rr].w + pa[rr].w;
                    *(float4*)(out + gbase) = o;
                }
            }
            __syncthreads();   // Ls reuse protection for next nb
        }
    }
}

// ---------------- launch ----------------
extern "C" void kernel_launch(void* const* d_in, const int* in_sizes, int n_in,
                              void* d_out, int out_size, void* d_ws, size_t ws_size,
                              hipStream_t stream)
{
    const float* f    = (const float*)d_in[0];
    const float* pf   = (const float*)d_in[1];
    const float* wf   = (const float*)d_in[2];
    const float* bfb  = (const float*)d_in[3];
    const float* wpf  = (const float*)d_in[4];
    const float* bpfb = (const float*)d_in[5];
    const float* w2   = (const float*)d_in[6];
    const float* b2   = (const float*)d_in[7];
    const float* pgw  = (const float*)d_in[8];
    const float* pgb  = (const float*)d_in[9];

    char* ws = (char*)d_ws;
    ushort* pg_img = (ushort*)(ws + 0);          // 2 MB
    ushort* w_img  = (ushort*)(ws + 2097152);    // 512 KB
    ushort* w2_img = (ushort*)(ws + 2621440);    // 256 KB
    float*  h_g    = (float*)(ws + 2883584);     // 1 MB  [256][1024]
    ushort* pf_g   = (ushort*)(ws + 3932160);    // 2 MB  [256][4096]
    float*  out    = (float*)d_out;

    k0_convert<<<dim3(704), dim3(256), 0, stream>>>(pgw, wf, wpf, w2, pg_img, w_img, w2_img);
    mega_ab<<<dim3(256), dim3(512), 0, stream>>>(f, pf, w_img, bfb, bpfb,
                                                 pg_img, pgb, h_g, pf_g);
    mega_cd<<<dim3(256), dim3(512), 0, stream>>>(f, pf, pg_img, pgb, w2_img, b2,
                                                 h_g, pf_g, out);
}

// Round 19
// 162.564 us; speedup vs baseline: 1.7317x; 1.0637x over previous
//
#include <hip/hip_runtime.h>
#include <stdint.h>

// DynamicFc R27: R18 fused structure + Phase-A staging PING-PONG.
//  R26 split measured: A+B = 44us (62%), C+D ~ 28us. B's L2 floor ~8us =>
//  Phase A ~ 30us. ab ran at 978 GB/s moving only 43MB => A is HBM-LATENCY
//  bound: 8 loads/thread in flight, covering window (16 MFMAs ~300-400cy at
//  2 waves/SIMD) < ~900cy HBM latency. Fix: vbufA/vbufB ping-pong — stage
//  s+2's loads issue when buffer s is consumed => window = rest of s + all
//  of s+1 ~ 1000-1500cy > 900cy. Static buffer choice (4-stage full unroll).
//  A regs: 64(vbufx2)+16(wfr)+8(c)+temps ~ 108 <= 128 budget (62464B LDS +
//  512thr keeps the proven 2-blk/4-wave allocator target; B peaks at ~120).
//  B/C/D + k0 R18-verbatim; split removed (+8us back).
// B=8192, F=1024, LOW=128, MID=32. p1: j=l*32+m (j<4096), p2: j=4096+m*128+l.
// Fragment-major images: chunk(T,ks)[lane][8] = W[T*16+(lane&15)][ks*32+(lane>>4)*8..+8]
// Tripwires: VGPR 110-125 (NOT 64), WRITE ~33MB, FETCH ~77MB, mega 56-63us.

typedef __attribute__((ext_vector_type(8))) short bf16x8;
typedef __attribute__((ext_vector_type(4))) float f32x4;

#define MFMA(a, b, c) __builtin_amdgcn_mfma_f32_16x16x32_bf16((a), (b), (c), 0, 0, 0)

__device__ __forceinline__ ushort f2bf(float x) {
    union { float f; uint32_t u; } v; v.f = x;
    return (ushort)((v.u + 0x7FFFu + ((v.u >> 16) & 1u)) >> 16);
}
__device__ __forceinline__ ushort4 f2bf4(float4 v) {
    ushort4 o; o.x = f2bf(v.x); o.y = f2bf(v.y); o.z = f2bf(v.z); o.w = f2bf(v.w); return o;
}
__device__ __forceinline__ float bf2f(ushort u) {
    union { uint32_t i; float f; } v; v.i = ((uint32_t)u) << 16; return v.f;
}

// ---------------- K0: convert + fragment-major re-layout (verified) ----------------
__global__ __launch_bounds__(256) void k0_convert(
    const float* __restrict__ pgw, const float* __restrict__ wf,
    const float* __restrict__ wpf, const float* __restrict__ w2,
    ushort* __restrict__ pg_img, ushort* __restrict__ w_img, ushort* __restrict__ w2_img)
{
    int cid = blockIdx.x * 256 + threadIdx.x;   // 704*256 = 180224
    const float* src; ushort* dst;
    if (cid < 131072) {                                  // pg: 512*4*64
        int lane = cid & 63, ks = (cid >> 6) & 3, T = cid >> 8;
        int j = T * 16 + (lane & 15), k = ks * 32 + (lane >> 4) * 8;
        src = pgw + (size_t)j * 128 + k;
        dst = pg_img + (size_t)cid * 8;
    } else if (cid < 163840) {                           // wf/wpf: 2*8*32*64
        int c = cid - 131072;
        int lane = c & 63, ks = (c >> 6) & 31, lt = (c >> 11) & 7, mat = c >> 14;
        int l = lt * 16 + (lane & 15), k = ks * 32 + (lane >> 4) * 8;
        src = (mat ? wpf : wf) + (size_t)l * 1024 + k;
        dst = w_img + (size_t)c * 8;
    } else {                                             // w2: 64*4*64
        int c = cid - 163840;
        int lane = c & 63, ks = (c >> 6) & 3, nt = c >> 8;
        int n = nt * 16 + (lane & 15), k = ks * 32 + (lane >> 4) * 8;
        src = w2 + (size_t)n * 128 + k;
        dst = w2_img + (size_t)c * 8;
    }
    float4 a = ((const float4*)src)[0], b = ((const float4*)src)[1];
    ((ushort4*)dst)[0] = f2bf4(a);
    ((ushort4*)dst)[1] = f2bf4(b);
}

// ---------------- MEGA: one block = 32 samples end-to-end, 8 waves ----------------
// grid 256 x 512 threads; 1 block/CU, 2 waves/SIMD.
__global__ __launch_bounds__(512, 2) void mega(
    const float* __restrict__ f, const float* __restrict__ pf,
    const ushort* __restrict__ w_img, const float* __restrict__ bfb,
    const float* __restrict__ bpfb, const ushort* __restrict__ pg_img,
    const float* __restrict__ pgb, const ushort* __restrict__ w2_img,
    const float* __restrict__ b2, float* __restrict__ out)
{
    __shared__ __align__(16) char smem[62464];
    // region0 (0..36864), phase-reused (R18 layout):
    //  A: As [32][520]us = 33280 | Tr [32][136]us (after As dead)
    //  B: hred [4][32][33]f = 16896 @0 | hl [32][32]f = 4096 @16896
    //  C: gLDS [128][33]f = 16896 @0 (hred dead; disjoint from hl)
    //  D: Ls [32][288]f = 36864 @0
    ushort* As    = (ushort*)smem;
    ushort* Tr    = (ushort*)smem;
    float*  hred  = (float*)smem;               // [4][32*33]
    float*  hl    = (float*)(smem + 16896);     // [32][32]
    float*  gLDS  = (float*)smem;               // [128][33]
    float*  Ls    = (float*)smem;               // [32][288]
    ushort* flowT = (ushort*)(smem + 36864);    // [128][36] bf16 = 9216 B
    ushort* pfrag = (ushort*)(smem + 46080);    // 8 chunks * 512 = 8192 B
    ushort* gfrag = (ushort*)(smem + 54272);    // 8 chunks * 512 = 8192 B

    const int tid = threadIdx.x;
    const int lane = tid & 63, wid = tid >> 6;   // wid 0..7
    const int q = lane >> 4, r15 = lane & 15;
    const int b0 = blockIdx.x * 32;

    // ============ Phase A: projections (PING-PONG staged, loads 2 stages deep) ======
    {
        float4 vbufA[8], vbufB[8];
        // preload stage 0 (f, kh=0) into A and stage 1 (f, kh=1) into B
#pragma unroll
        for (int rr = 0; rr < 8; rr++) {
            int row = rr * 4 + (tid >> 7);
            vbufA[rr] = *(const float4*)(f + (size_t)(b0 + row) * 1024 + (tid & 127) * 4);
        }
#pragma unroll
        for (int rr = 0; rr < 8; rr++) {
            int row = rr * 4 + (tid >> 7);
            vbufB[rr] = *(const float4*)(f + (size_t)(b0 + row) * 1024 + 512 + (tid & 127) * 4);
        }
        f32x4 c[2];
        float bias_v = 0.f;
#pragma unroll
        for (int s = 0; s < 4; s++) {            // (mat,kh) = (0,0)(0,1)(1,0)(1,1)
            const int mat = s >> 1, kh = s & 1;
            if (kh == 0) {
                c[0] = (f32x4){0.f, 0.f, 0.f, 0.f};
                c[1] = (f32x4){0.f, 0.f, 0.f, 0.f};
                bias_v = (mat ? bpfb : bfb)[wid * 16 + r15];
            }
            __syncthreads();                     // prior As readers done
            // write As from the buffer for stage s (static: A for even s, B for odd)
            if ((s & 1) == 0) {
#pragma unroll
                for (int rr = 0; rr < 8; rr++) {
                    int row = rr * 4 + (tid >> 7);
                    *(ushort4*)(As + row * 520 + (tid & 127) * 4) = f2bf4(vbufA[rr]);
                }
            } else {
#pragma unroll
                for (int rr = 0; rr < 8; rr++) {
                    int row = rr * 4 + (tid >> 7);
                    *(ushort4*)(As + row * 520 + (tid & 127) * 4) = f2bf4(vbufB[rr]);
                }
            }
            __syncthreads();
            if (s < 2) {                         // refill the just-freed buffer: stage s+2
                const int sn = s + 2, khn = sn & 1;   // mat of s+2 is always 1 (pf)
                if ((s & 1) == 0) {
#pragma unroll
                    for (int rr = 0; rr < 8; rr++) {
                        int row = rr * 4 + (tid >> 7);
                        vbufA[rr] = *(const float4*)(pf + (size_t)(b0 + row) * 1024 + khn * 512 + (tid & 127) * 4);
                    }
                } else {
#pragma unroll
                    for (int rr = 0; rr < 8; rr++) {
                        int row = rr * 4 + (tid >> 7);
                        vbufB[rr] = *(const float4*)(pf + (size_t)(b0 + row) * 1024 + khn * 512 + (tid & 127) * 4);
                    }
                }
            }
            const ushort* wb = w_img + (size_t)mat * 131072 + ((size_t)wid * 32 + kh * 16) * 512;
            bf16x8 wfr[4];
#pragma unroll
            for (int p = 0; p < 4; p++) wfr[p] = *(const bf16x8*)(wb + (size_t)p * 512 + lane * 8);
#pragma unroll
            for (int ks = 0; ks < 16; ks++) {    // full unroll, ring-4
                const int cur = ks & 3;
                bf16x8 a0 = *(const bf16x8*)(As + (size_t)r15 * 520 + ks * 32 + q * 8);
                bf16x8 a1 = *(const bf16x8*)(As + (size_t)(16 + r15) * 520 + ks * 32 + q * 8);
                c[0] = MFMA(a0, wfr[cur], c[0]);
                c[1] = MFMA(a1, wfr[cur], c[1]);
                if (ks + 4 < 16)
                    wfr[cur] = *(const bf16x8*)(wb + (size_t)(ks + 4) * 512 + lane * 8);
            }
            // C: row = b_local (mt*16 + q*4 + r), col = l (wid*16 + r15)
            if (s == 1) {                        // mat0 epilogue -> flowT (disjoint)
                int l = wid * 16 + r15;
#pragma unroll
                for (int mt = 0; mt < 2; mt++)
#pragma unroll
                    for (int r = 0; r < 4; r++)
                        flowT[l * 36 + mt * 16 + q * 4 + r] = f2bf(c[mt][r] + bias_v);
            }
            if (s == 3) {                        // mat1 epilogue -> Tr -> pfrag
                __syncthreads();                 // all As reads done before Tr overwrite
                int l = wid * 16 + r15;
#pragma unroll
                for (int mt = 0; mt < 2; mt++)
#pragma unroll
                    for (int r = 0; r < 4; r++)
                        Tr[(mt * 16 + q * 4 + r) * 136 + l] = f2bf(c[mt][r] + bias_v);
                __syncthreads();
                // emit pfrag: one chunk per wave (chunkid = wid = bt*4 + ks2)
                int bt = wid >> 2, ks2 = wid & 3;
                int k0 = ks2 * 32 + (lane >> 4) * 8;
                uint4 tv = *(const uint4*)(Tr + (size_t)(bt * 16 + (lane & 15)) * 136 + k0);
                *(uint4*)(pfrag + (size_t)wid * 512 + lane * 8) = tv;
            }
        }
    }
    __syncthreads();   // pfrag/flowT visible to all waves

    // ========= Phase B: h — wave=(mh,lq), outer8 x inner4 ring-4, 4 partials ========
    bf16x8 bfr[2][4];  // pf_low fragments, held through B and C
#pragma unroll
    for (int ct = 0; ct < 2; ct++)
#pragma unroll
        for (int ks = 0; ks < 4; ks++)
            bfr[ct][ks] = *(const bf16x8*)(pfrag + (size_t)(ct * 4 + ks) * 512 + lane * 8);

    {
        const int mh = wid & 1, lq = wid >> 1;   // m-half, l-quarter
        f32x4 hacc[2];                           // [ct]
        hacc[0] = (f32x4){0.f, 0.f, 0.f, 0.f};
        hacc[1] = (f32x4){0.f, 0.f, 0.f, 0.f};

        bf16x8 af[4][4];
        f32x4 bvr[4];
#pragma unroll
        for (int t = 0; t < 4; t++) {            // preload: p1 tile T = l*2 + mh
            const int T = (lq * 32 + t) * 2 + mh;
            const ushort* ap = pg_img + (size_t)T * 2048;
#pragma unroll
            for (int ks = 0; ks < 4; ks++)
                af[t][ks] = *(const bf16x8*)(ap + ks * 512 + lane * 8);
            bvr[t] = *(const f32x4*)(pgb + (size_t)T * 16 + q * 4);
        }
#pragma unroll 1
        for (int to = 0; to < 8; to++) {         // BOUNDED window
#pragma unroll
            for (int ti = 0; ti < 4; ti++) {     // ring idx (to*4+ti)&3 == ti: static
                const int t = to * 4 + ti;
                const int l = lq * 32 + t;
                f32x4 bv = bvr[ti];
#pragma unroll
                for (int ct = 0; ct < 2; ct++) {
                    f32x4 cc = (f32x4){0.f, 0.f, 0.f, 0.f};
#pragma unroll
                    for (int ks = 0; ks < 4; ks++) cc = MFMA(af[ti][ks], bfr[ct][ks], cc);
                    float s = bf2f(flowT[l * 36 + ct * 16 + r15]);
#pragma unroll
                    for (int r = 0; r < 4; r++) hacc[ct][r] += s * (cc[r] + bv[r]);
                }
                if (t + 4 < 32) {
                    const int Tn = (l + 4) * 2 + mh;
                    const ushort* ap = pg_img + (size_t)Tn * 2048;
#pragma unroll
                    for (int ks = 0; ks < 4; ks++)
                        af[ti][ks] = *(const bf16x8*)(ap + ks * 512 + lane * 8);
                    bvr[ti] = *(const f32x4*)(pgb + (size_t)Tn * 16 + q * 4);
                }
            }
        }
#pragma unroll
        for (int ct = 0; ct < 2; ct++)
#pragma unroll
            for (int r = 0; r < 4; r++)
                hred[lq * 1056 + (mh * 16 + q * 4 + r) * 33 + ct * 16 + r15] = hacc[ct][r];
    }
    __syncthreads();
    {   // 4-partial reduce + relu -> hl [32 m][32 b]; 512 threads, 2 floats each
        int m = tid >> 4, bc = (tid & 15) * 2;
        float s0 = 0.f, s1 = 0.f;
#pragma unroll
        for (int w = 0; w < 4; w++) {
            s0 += hred[w * 1056 + m * 33 + bc];
            s1 += hred[w * 1056 + m * 33 + bc + 1];
        }
        hl[m * 32 + bc]     = fmaxf(s0, 0.f);
        hl[m * 32 + bc + 1] = fmaxf(s1, 0.f);
    }
    __syncthreads();

    // ===== Phase C: g — wave owns l-tile wid, 32 m as outer8 x inner4 ring-4 ========
    {
        f32x4 gacc[2];                           // [ct]
        gacc[0] = (f32x4){0.f, 0.f, 0.f, 0.f};
        gacc[1] = (f32x4){0.f, 0.f, 0.f, 0.f};

        bf16x8 afc[4][4];
        f32x4 bvc[4];
#pragma unroll
        for (int t = 0; t < 4; t++) {            // preload: p2 tile T = 256 + m*8 + wid
            const ushort* ap = pg_img + (size_t)(256 + t * 8 + wid) * 2048;
#pragma unroll
            for (int ks = 0; ks < 4; ks++)
                afc[t][ks] = *(const bf16x8*)(ap + ks * 512 + lane * 8);
            bvc[t] = *(const f32x4*)(pgb + 4096 + (size_t)t * 128 + wid * 16 + q * 4);
        }
#pragma unroll 1
        for (int mo = 0; mo < 8; mo++) {         // BOUNDED window
#pragma unroll
            for (int mi = 0; mi < 4; mi++) {     // ring idx (mo*4+mi)&3 == mi: static
                const int m = mo * 4 + mi;
                f32x4 bv = bvc[mi];
#pragma unroll
                for (int ct = 0; ct < 2; ct++) {
                    f32x4 cc = (f32x4){0.f, 0.f, 0.f, 0.f};
#pragma unroll
                    for (int ks = 0; ks < 4; ks++) cc = MFMA(afc[mi][ks], bfr[ct][ks], cc);
                    float s = hl[m * 32 + ct * 16 + r15];   // broadcast read
#pragma unroll
                    for (int r = 0; r < 4; r++) gacc[ct][r] += s * (cc[r] + bv[r]);
                }
                if (m + 4 < 32) {
                    const int mn = m + 4;
                    const ushort* ap = pg_img + (size_t)(256 + mn * 8 + wid) * 2048;
#pragma unroll
                    for (int ks = 0; ks < 4; ks++)
                        afc[mi][ks] = *(const bf16x8*)(ap + ks * 512 + lane * 8);
                    bvc[mi] = *(const f32x4*)(pgb + 4096 + (size_t)mn * 128 + wid * 16 + q * 4);
                }
            }
        }
        // full m-sum done in-wave: write [16 l][32 b] patch to gLDS (pad 33)
#pragma unroll
        for (int ct = 0; ct < 2; ct++)
#pragma unroll
            for (int r = 0; r < 4; r++)
                gLDS[(size_t)(wid * 16 + q * 4 + r) * 33 + ct * 16 + r15] = gacc[ct][r];
    }
    __syncthreads();
    {   // emit gfrag: chunk wid = (bt = wid>>2, ksl = wid&3)
        const int bt = wid >> 2, ksl = wid & 3;
        const int bloc = bt * 16 + (lane & 15);
        const int l0 = ksl * 32 + (lane >> 4) * 8;
        ushort tmp[8];
#pragma unroll
        for (int e = 0; e < 8; e++)
            tmp[e] = f2bf(gLDS[(size_t)(l0 + e) * 33 + bloc]);
        ushort4 lo = {tmp[0], tmp[1], tmp[2], tmp[3]};
        ushort4 hi = {tmp[4], tmp[5], tmp[6], tmp[7]};
        ushort* dst = gfrag + (size_t)wid * 512 + lane * 8;
        ((ushort4*)dst)[0] = lo;
        ((ushort4*)dst)[1] = hi;
    }
    __syncthreads();

    // ================= Phase D: out (lean w2r, nb loop unroll 1) ====================
    {
        bf16x8 afg[2][4];
#pragma unroll
        for (int mtl = 0; mtl < 2; mtl++)
#pragma unroll
            for (int ks = 0; ks < 4; ks++)
                afg[mtl][ks] = *(const bf16x8*)(gfrag + (size_t)(mtl * 4 + ks) * 512 + lane * 8);

#pragma unroll 1
        for (int nb = 0; nb < 4; nb++) {         // BOUNDED window
            const int n0 = nb * 256;
            // early epilogue loads: land before the post-Ls barrier
            float4 fa[4], pa[4];
#pragma unroll
            for (int rr = 0; rr < 4; rr++) {
                const int b = b0 + wid * 4 + rr;
                const size_t gbase = (size_t)b * 1024 + n0 + lane * 4;
                fa[rr] = *(const float4*)(f + gbase);
                pa[rr] = *(const float4*)(pf + gbase);
            }
            float bias_v2[2];
#pragma unroll
            for (int nt = 0; nt < 2; nt++) bias_v2[nt] = b2[nb * 256 + wid * 32 + nt * 16 + r15];
            bf16x8 w2r[2][4];
#pragma unroll
            for (int nt = 0; nt < 2; nt++)
#pragma unroll
                for (int ks = 0; ks < 4; ks++)
                    w2r[nt][ks] = *(const bf16x8*)(w2_img + (size_t)((nb * 16 + wid * 2 + nt) * 4 + ks) * 512 + lane * 8);
#pragma unroll
            for (int nt = 0; nt < 2; nt++) {
#pragma unroll
                for (int mtl = 0; mtl < 2; mtl++) {
                    f32x4 cc = (f32x4){0.f, 0.f, 0.f, 0.f};
#pragma unroll
                    for (int ks = 0; ks < 4; ks++) cc = MFMA(afg[mtl][ks], w2r[nt][ks], cc);
                    const int nloc = wid * 32 + nt * 16 + r15;        // 0..255
                    const int chunk = nloc >> 5, within = nloc & 31;
#pragma unroll
                    for (int r = 0; r < 4; r++)
                        Ls[(size_t)(mtl * 16 + q * 4 + r) * 288 + chunk * 36 + within] = cc[r] + bias_v2[nt];
                }
            }
            __syncthreads();
            {   // wave-contiguous epilogue: wave w rows w*4..+4, lane i <-> n0+4i
                const float* ls = Ls + (size_t)(wid * 4) * 288 + (lane >> 3) * 36 + (lane & 7) * 4;
#pragma unroll
                for (int rr = 0; rr < 4; rr++) {
                    const int b = b0 + wid * 4 + rr;
                    const size_t gbase = (size_t)b * 1024 + n0 + lane * 4;
                    float4 lv = *(const float4*)(ls + rr * 288);
                    float4 o;
                    o.x = lv.x + fa[rr].x + pa[rr].x; o.y = lv.y + fa[rr].y + pa[rr].y;
                    o.z = lv.z + fa[rr].z + pa[rr].z; o.w = lv.w + fa[rr].w + pa[rr].w;
                    *(float4*)(out + gbase) = o;
                }
            }
            __syncthreads();   // Ls reuse protection for next nb
        }
    }
}

// ---------------- launch ----------------
extern "C" void kernel_launch(void* const* d_in, const int* in_sizes, int n_in,
                              void* d_out, int out_size, void* d_ws, size_t ws_size,
                              hipStream_t stream)
{
    const float* f    = (const float*)d_in[0];
    const float* pf   = (const float*)d_in[1];
    const float* wf   = (const float*)d_in[2];
    const float* bfb  = (const float*)d_in[3];
    const float* wpf  = (const float*)d_in[4];
    const float* bpfb = (const float*)d_in[5];
    const float* w2   = (const float*)d_in[6];
    const float* b2   = (const float*)d_in[7];
    const float* pgw  = (const float*)d_in[8];
    const float* pgb  = (const float*)d_in[9];

    char* ws = (char*)d_ws;
    ushort* pg_img = (ushort*)(ws + 0);          // 2 MB
    ushort* w_img  = (ushort*)(ws + 2097152);    // 512 KB
    ushort* w2_img = (ushort*)(ws + 2621440);    // 256 KB
    float*  out    = (float*)d_out;

    k0_convert<<<dim3(704), dim3(256), 0, stream>>>(pgw, wf, wpf, w2, pg_img, w_img, w2_img);
    mega<<<dim3(256), dim3(512), 0, stream>>>(f, pf, w_img, bfb, bpfb,
                                              pg_img, pgb, w2_img, b2, out);
}